// Round 3
// baseline (214.123 us; speedup 1.0000x reference)
//
#include <hip/hip_runtime.h>
#include <hip/hip_bf16.h>
#include <math.h>

#define EPS 1e-6f
#define TAU 1.0f

typedef float v4f __attribute__((ext_vector_type(4)));

__device__ __forceinline__ float gd_loss_one(
        float px, float py, float pw, float ph, float pr,
        float tx, float ty, float tw, float th, float tr) {
    pw = fminf(fmaxf(pw, 1e-7f), 1e7f);
    ph = fminf(fmaxf(ph, 1e-7f), 1e7f);
    float pa = 0.25f * pw * pw;
    float pb = 0.25f * ph * ph;
    float ps, pc;
    __sincosf(pr, &ps, &pc);
    float p11 = pa * pc * pc + pb * ps * ps;
    float p12 = (pa - pb) * ps * pc;
    float p22 = pa * ps * ps + pb * pc * pc;

    tw = fminf(fmaxf(tw, 1e-7f), 1e7f);
    th = fminf(fmaxf(th, 1e-7f), 1e7f);
    float ta = 0.25f * tw * tw;
    float tb = 0.25f * th * th;
    float ts, tc;
    __sincosf(tr, &ts, &tc);
    float t11 = ta * tc * tc + tb * ts * ts;
    float t12 = (ta - tb) * ts * tc;
    float t22 = ta * ts * ts + tb * tc * tc;

    float det_p = p11 * p22 - p12 * p12;
    float det_t = t11 * t22 - t12 * t12;

    float dx = px - tx;
    float dy = py - ty;

    float inv_det_t = __frcp_rn(det_t);
    float term1 = (t22 * dx * dx - 2.0f * t12 * dx * dy + t11 * dy * dy) * inv_det_t;
    float trace_term = (t22 * p11 - 2.0f * t12 * p12 + t11 * p22) * inv_det_t;
    float term2 = trace_term + __logf(det_t) - __logf(det_p);

    float dis = term1 + term2 - 2.0f;
    float kl = fmaxf(dis, EPS);
    return 1.0f - 1.0f / (TAU + sqrtf(kl));
}

// 4 boxes per thread; all 10 input float4 loads issued non-temporally up front.
__global__ void __launch_bounds__(256, 8) gd_loss_kernel_nt(
        const v4f* __restrict__ pred4,
        const v4f* __restrict__ tgt4,
        v4f* __restrict__ out4, int nq) {
    int i = blockIdx.x * blockDim.x + threadIdx.x;
    if (i >= nq) return;

    v4f pv[5], tv[5];
    #pragma unroll
    for (int k = 0; k < 5; k++)
        pv[k] = __builtin_nontemporal_load(&pred4[(size_t)i * 5 + k]);
    #pragma unroll
    for (int k = 0; k < 5; k++)
        tv[k] = __builtin_nontemporal_load(&tgt4[(size_t)i * 5 + k]);

    float pf[20], tf[20];
    #pragma unroll
    for (int k = 0; k < 5; k++) {
        #pragma unroll
        for (int j = 0; j < 4; j++) {
            pf[4 * k + j] = pv[k][j];
            tf[4 * k + j] = tv[k][j];
        }
    }

    v4f res;
    #pragma unroll
    for (int b = 0; b < 4; b++) {
        res[b] = gd_loss_one(pf[b * 5 + 0], pf[b * 5 + 1], pf[b * 5 + 2], pf[b * 5 + 3], pf[b * 5 + 4],
                             tf[b * 5 + 0], tf[b * 5 + 1], tf[b * 5 + 2], tf[b * 5 + 3], tf[b * 5 + 4]);
    }
    __builtin_nontemporal_store(res, &out4[i]);
}

__global__ void gd_loss_tail(
        const float* __restrict__ pred,
        const float* __restrict__ tgt,
        float* __restrict__ out, int start, int n) {
    int i = start + blockIdx.x * blockDim.x + threadIdx.x;
    if (i >= n) return;
    const float* p = pred + (size_t)i * 5;
    const float* t = tgt + (size_t)i * 5;
    out[i] = gd_loss_one(p[0], p[1], p[2], p[3], p[4],
                         t[0], t[1], t[2], t[3], t[4]);
}

extern "C" void kernel_launch(void* const* d_in, const int* in_sizes, int n_in,
                              void* d_out, int out_size, void* d_ws, size_t ws_size,
                              hipStream_t stream) {
    const float* pred = (const float*)d_in[0];
    const float* tgt  = (const float*)d_in[1];
    float* out = (float*)d_out;
    int n = out_size;

    int nq = n / 4;
    int rem = n - nq * 4;

    if (nq > 0) {
        int block = 256;
        int grid = (nq + block - 1) / block;
        gd_loss_kernel_nt<<<grid, block, 0, stream>>>(
            (const v4f*)pred, (const v4f*)tgt, (v4f*)out, nq);
    }
    if (rem > 0) {
        gd_loss_tail<<<1, 64, 0, stream>>>(pred, tgt, out, nq * 4, n);
    }
}

// Round 4
// 187.259 us; speedup vs baseline: 1.1435x; 1.1435x over previous
//
#include <hip/hip_runtime.h>
#include <hip/hip_bf16.h>
#include <math.h>

#define EPS 1e-6f
#define TAU 1.0f

typedef float v4f __attribute__((ext_vector_type(4)));

__device__ __forceinline__ float gd_loss_one(
        float px, float py, float pw, float ph, float pr,
        float tx, float ty, float tw, float th, float tr) {
    pw = fminf(fmaxf(pw, 1e-7f), 1e7f);
    ph = fminf(fmaxf(ph, 1e-7f), 1e7f);
    float pa = 0.25f * pw * pw;
    float pb = 0.25f * ph * ph;
    float ps, pc;
    __sincosf(pr, &ps, &pc);
    float p11 = pa * pc * pc + pb * ps * ps;
    float p12 = (pa - pb) * ps * pc;
    float p22 = pa * ps * ps + pb * pc * pc;

    tw = fminf(fmaxf(tw, 1e-7f), 1e7f);
    th = fminf(fmaxf(th, 1e-7f), 1e7f);
    float ta = 0.25f * tw * tw;
    float tb = 0.25f * th * th;
    float ts, tc;
    __sincosf(tr, &ts, &tc);
    float t11 = ta * tc * tc + tb * ts * ts;
    float t12 = (ta - tb) * ts * tc;
    float t22 = ta * ts * ts + tb * tc * tc;

    float det_p = p11 * p22 - p12 * p12;
    float det_t = t11 * t22 - t12 * t12;

    float dx = px - tx;
    float dy = py - ty;

    float inv_det_t = __frcp_rn(det_t);
    float term1 = (t22 * dx * dx - 2.0f * t12 * dx * dy + t11 * dy * dy) * inv_det_t;
    float trace_term = (t22 * p11 - 2.0f * t12 * p12 + t11 * p22) * inv_det_t;
    float term2 = trace_term + __logf(det_t) - __logf(det_p);

    float dis = term1 + term2 - 2.0f;
    float kl = fmaxf(dis, EPS);
    return 1.0f - 1.0f / (TAU + sqrtf(kl));
}

// Tile of 1024 boxes per 256-thread block.
// Load phase: 5 fully-coalesced float4 loads per input (copy-kernel pattern).
// Compute phase: per-thread ds_read_b128 x5 per input (16B-aligned, conflict-free).
__global__ void __launch_bounds__(256) gd_loss_lds(
        const v4f* __restrict__ pred4,
        const v4f* __restrict__ tgt4,
        v4f* __restrict__ out4, int nq) {           // nq = n/4 box-quads
    __shared__ float p_lds[5120];                   // 1024 boxes * 5 floats
    __shared__ float t_lds[5120];

    int tid = threadIdx.x;
    size_t tile = blockIdx.x;
    size_t f4base = tile * 1280;                    // 1280 float4 per input tile
    size_t nf4 = (size_t)nq * 5;                    // total float4 per input

    v4f* pl4 = (v4f*)p_lds;
    v4f* tl4 = (v4f*)t_lds;

    #pragma unroll
    for (int k = 0; k < 5; k++) {
        size_t idx = f4base + k * 256 + tid;
        if (idx < nf4) {
            pl4[k * 256 + tid] = pred4[idx];
            tl4[k * 256 + tid] = tgt4[idx];
        }
    }
    __syncthreads();

    size_t q = tile * 256 + tid;                    // this thread's box-quad
    if (q >= (size_t)nq) return;

    v4f pv[5], tv[5];
    #pragma unroll
    for (int k = 0; k < 5; k++) {
        pv[k] = pl4[tid * 5 + k];                   // 80B stride, 16B aligned
        tv[k] = tl4[tid * 5 + k];
    }

    float pf[20], tf[20];
    #pragma unroll
    for (int k = 0; k < 5; k++) {
        #pragma unroll
        for (int j = 0; j < 4; j++) {
            pf[4 * k + j] = pv[k][j];
            tf[4 * k + j] = tv[k][j];
        }
    }

    v4f res;
    #pragma unroll
    for (int b = 0; b < 4; b++) {
        res[b] = gd_loss_one(pf[b * 5 + 0], pf[b * 5 + 1], pf[b * 5 + 2], pf[b * 5 + 3], pf[b * 5 + 4],
                             tf[b * 5 + 0], tf[b * 5 + 1], tf[b * 5 + 2], tf[b * 5 + 3], tf[b * 5 + 4]);
    }
    out4[q] = res;
}

__global__ void gd_loss_tail(
        const float* __restrict__ pred,
        const float* __restrict__ tgt,
        float* __restrict__ out, int start, int n) {
    int i = start + blockIdx.x * blockDim.x + threadIdx.x;
    if (i >= n) return;
    const float* p = pred + (size_t)i * 5;
    const float* t = tgt + (size_t)i * 5;
    out[i] = gd_loss_one(p[0], p[1], p[2], p[3], p[4],
                         t[0], t[1], t[2], t[3], t[4]);
}

extern "C" void kernel_launch(void* const* d_in, const int* in_sizes, int n_in,
                              void* d_out, int out_size, void* d_ws, size_t ws_size,
                              hipStream_t stream) {
    const float* pred = (const float*)d_in[0];
    const float* tgt  = (const float*)d_in[1];
    float* out = (float*)d_out;
    int n = out_size;

    int nq = n / 4;
    int rem = n - nq * 4;

    if (nq > 0) {
        int grid = (nq + 255) / 256;                // 256 box-quads per block
        gd_loss_lds<<<grid, 256, 0, stream>>>(
            (const v4f*)pred, (const v4f*)tgt, (v4f*)out, nq);
    }
    if (rem > 0) {
        gd_loss_tail<<<1, 64, 0, stream>>>(pred, tgt, out, nq * 4, n);
    }
}